// Round 15
// baseline (528.089 us; speedup 1.0000x reference)
//
#include <hip/hip_runtime.h>

#define TT 256   // T
#define BB 512   // B
#define NG 256   // 4*H
#define KIN 128  // input width for both layers

typedef _Float16 half2v __attribute__((ext_vector_type(2)));
typedef _Float16 half4v __attribute__((ext_vector_type(4)));
typedef _Float16 half8v __attribute__((ext_vector_type(8)));
typedef float float4v __attribute__((ext_vector_type(4)));

__device__ __forceinline__ float sig_(float x){ return 1.f/(1.f+__expf(-x)); }
__device__ __forceinline__ float th_(float x){ return fmaf(2.f, 1.f/(1.f+__expf(-2.f*x)), -1.f); }

#if __has_builtin(__builtin_amdgcn_fdot2)
__device__ __forceinline__ float fdot2_(half2v a, half2v b, float c){
  return __builtin_amdgcn_fdot2(a, b, c, false);
}
#else
__device__ __forceinline__ float fdot2_(half2v a, half2v b, float c){
  return c + (float)a[0]*(float)b[0] + (float)a[1]*(float)b[1];
}
#endif

#define SV2(v,k) __builtin_shufflevector((v),(v), 2*(k), 2*(k)+1)

__device__ __forceinline__ half4v ld4h(const float* p){
  float4v v = *reinterpret_cast<const float4v*>(p);
  half4v h; h[0]=(_Float16)v[0]; h[1]=(_Float16)v[1]; h[2]=(_Float16)v[2]; h[3]=(_Float16)v[3];
  return h;
}

// ---- one-shot weight conversion fp32 -> fp16 into ws pool (row-major) ----
// halves offsets: wih_l0f 0, wih_l0r 32768, wih_l1f 65536,
//                 whh_l0f 98304, whh_l0r 114688, whh_l1f 131072
__global__ __launch_bounds__(256)
void conv_weights(const float* __restrict__ s0, const float* __restrict__ s1,
                  const float* __restrict__ s2, const float* __restrict__ s3,
                  const float* __restrict__ s4, const float* __restrict__ s5,
                  _Float16* __restrict__ dst)
{
  const int bid = blockIdx.x, tid = threadIdx.x;
  const float* src; int off, idx;
  if (bid < 128)      { src=s0; off=0;      idx=bid*256+tid; }
  else if (bid < 256) { src=s1; off=32768;  idx=(bid-128)*256+tid; }
  else if (bid < 384) { src=s2; off=65536;  idx=(bid-256)*256+tid; }
  else if (bid < 448) { src=s3; off=98304;  idx=(bid-384)*256+tid; }
  else if (bid < 512) { src=s4; off=114688; idx=(bid-448)*256+tid; }
  else                { src=s5; off=131072; idx=(bid-512)*256+tid; }
  dst[off+idx] = (_Float16)src[idx];
}

// C[m][n] = sum_k A[m][k]*W[n][k] + bias[n], written fp16 (b-major).
template<typename AT>
__global__ __launch_bounds__(256)
void gemm_xg(const AT* __restrict__ A, const _Float16* __restrict__ W16,
             const float* __restrict__ bias, _Float16* __restrict__ Cout)
{
  __shared__ __align__(16) _Float16 aL[64][72];
  __shared__ __align__(16) _Float16 wL[256][72];
  const int tid  = threadIdx.x;
  const int wave = tid >> 6;
  const int lane = tid & 63;
  const int lr   = lane & 15;
  const int kg   = lane >> 4;
  const size_t m0 = (size_t)blockIdx.x * 64;

  float4v acc[4][4];
  #pragma unroll
  for (int a=0;a<4;a++)
    #pragma unroll
    for (int b=0;b<4;b++)
      acc[a][b] = float4v{0.f,0.f,0.f,0.f};

  for (int kc = 0; kc < KIN; kc += 64) {
    if constexpr (__is_same(AT, float)) {
      #pragma unroll
      for (int q=0;q<4;q++){
        int fi = tid + q*256;
        int r = fi >> 4, c4 = (fi & 15)*4;
        *reinterpret_cast<half4v*>(&aL[r][c4]) = ld4h(&A[(m0+(size_t)r)*KIN + kc + c4]);
      }
    } else {
      #pragma unroll
      for (int q=0;q<2;q++){
        int fi = tid + q*256;
        int r = fi >> 3, c8 = (fi & 7)*8;
        *reinterpret_cast<half8v*>(&aL[r][c8]) =
            *reinterpret_cast<const half8v*>(&A[(m0+(size_t)r)*KIN + kc + c8]);
      }
    }
    #pragma unroll
    for (int q=0;q<8;q++){
      int fi = tid + q*256;
      int n = fi >> 3, c8 = (fi & 7)*8;
      *reinterpret_cast<half8v*>(&wL[n][c8]) =
          *reinterpret_cast<const half8v*>(&W16[(size_t)n*KIN + kc + c8]);
    }
    __syncthreads();
    #pragma unroll
    for (int ks=0; ks<64; ks+=32){
      half8v af[4], bf[4];
      #pragma unroll
      for (int rt=0;rt<4;rt++)
        af[rt] = *reinterpret_cast<const half8v*>(&aL[rt*16+lr][ks + kg*8]);
      #pragma unroll
      for (int ct=0;ct<4;ct++)
        bf[ct] = *reinterpret_cast<const half8v*>(&wL[wave*64 + ct*16 + lr][ks + kg*8]);
      #pragma unroll
      for (int rt=0;rt<4;rt++)
        #pragma unroll
        for (int ct=0;ct<4;ct++)
          acc[rt][ct] = __builtin_amdgcn_mfma_f32_16x16x32_f16(af[rt], bf[ct], acc[rt][ct], 0,0,0);
    }
    __syncthreads();
  }
  #pragma unroll
  for (int ct=0;ct<4;ct++){
    const int col = wave*64 + ct*16 + lr;
    const float bv = bias[col];
    #pragma unroll
    for (int rt=0;rt<4;rt++){
      const size_t rbase = m0 + rt*16 + kg*4;
      #pragma unroll
      for (int i=0;i<4;i++)
        Cout[(rbase+(size_t)i)*NG + col] = (_Float16)(acc[rt][ct][i] + bv);
    }
  }
}

// r15 scan = r8 skeleton (wave=gate, private hs4, ping-pong acts, ONE barrier,
// ring-8) + instruction diet:
//  * NR rows per wave: weight value extracted once feeds NR fdot2s (halves the
//    per-row AGPR-copy / weight-access cost that made r8 ~166 instr/step).
//  * ALL global accesses are pointer+constant-stride increments (kills the
//    per-step 64-bit address arithmetic for xg ring and x1out stores).
template<int NR, int MODE>
__global__ __launch_bounds__(256, 4)
void lstm_scan_d(const _Float16* __restrict__ xgPool,   // fwd 0, rev +BB*TT*NG
                 const _Float16* __restrict__ whhPool,  // fwd 0, rev +16384
                 int nF,
                 _Float16* __restrict__ x1out, float* __restrict__ hfin)
{
  const int tid = threadIdx.x;
  const int w   = tid >> 6;        // wave id = gate id (0:i 1:f 2:g 3:o)
  const int j   = tid & 63;        // unit within gate; gate row = tid
  const bool rev = (int)blockIdx.x >= nF;
  const int bblk = rev ? ((int)blockIdx.x - nF) : (int)blockIdx.x;
  const int r0 = bblk * NR;
  const _Float16* xg  = xgPool  + (rev ? (size_t)BB*TT*NG : 0);
  const _Float16* whh = whhPool + (rev ? (size_t)16384 : 0);

  __shared__ __align__(16) float acts[2][NR][256];
  __shared__ __align__(16) _Float16 hs4[4][NR][64];

  // w_hh row tid (= gate w, unit row j): 8 half8v
  half8v wreg[8];
  #pragma unroll
  for (int q=0;q<8;q++)
    wreg[q] = *reinterpret_cast<const half8v*>(&whh[(size_t)tid*64 + q*8]);

  hs4[w][0][j] = (_Float16)0.f;
  if constexpr (NR==2) hs4[w][1][j] = (_Float16)0.f;
  float c0 = 0.f, c1 = 0.f, hl0 = 0.f, hl1 = 0.f;
  __syncthreads();

  // xg pointers: stride dT per step (halves)
  const ptrdiff_t dT = rev ? -(ptrdiff_t)NG : (ptrdiff_t)NG;
  const int tstart = rev ? (TT-1) : 0;
  const _Float16* pa0 = xg + ((size_t)(r0+0)*TT + tstart)*NG + tid;
  const _Float16* pa1 = (NR==2) ? (xg + ((size_t)(r0+1)*TT + tstart)*NG + tid) : pa0;

  _Float16 rg0[8], rg1[8];
  #pragma unroll
  for (int u=0;u<8;u++){
    rg0[u] = *pa0; pa0 += dT;
    if constexpr (NR==2){ rg1[u] = *pa1; pa1 += dT; }
  }

  // x1 store pointers: wave r stores row r; stride dX per step
  const ptrdiff_t dX = rev ? -(ptrdiff_t)128 : (ptrdiff_t)128;
  const int xoff = rev ? 64 : 0;
  _Float16* q0 = (MODE==0) ? x1out + ((size_t)(r0+0)*TT + tstart)*128 + xoff + j : nullptr;
  _Float16* q1 = (MODE==0 && NR==2) ? x1out + ((size_t)(r0+1)*TT + tstart)*128 + xoff + j : nullptr;

  for (int tb=0; tb<TT; tb+=8){
    #pragma unroll
    for (int u=0;u<8;u++){
      const int tt = tb + u;
      const int par = tt & 1;

      const float xp0 = (float)rg0[u];
      float xp1 = 0.f;
      if constexpr (NR==2) xp1 = (float)rg1[u];
      if (tt+8 < TT){
        rg0[u] = *pa0; pa0 += dT;
        if constexpr (NR==2){ rg1[u] = *pa1; pa1 += dT; }
      }

      // dots: weight value extracted ONCE, feeds both rows
      float a0=0.f, b0=0.f, a1=0.f, b1=0.f;
      #pragma unroll
      for (int q=0;q<8;q++){
        const half8v w8 = wreg[q];
        const half8v h80 = *reinterpret_cast<const half8v*>(&hs4[w][0][q*8]);
        a0 = fdot2_(SV2(w8,0), SV2(h80,0), a0);
        b0 = fdot2_(SV2(w8,1), SV2(h80,1), b0);
        a0 = fdot2_(SV2(w8,2), SV2(h80,2), a0);
        b0 = fdot2_(SV2(w8,3), SV2(h80,3), b0);
        if constexpr (NR==2){
          const half8v h81 = *reinterpret_cast<const half8v*>(&hs4[w][1][q*8]);
          a1 = fdot2_(SV2(w8,0), SV2(h81,0), a1);
          b1 = fdot2_(SV2(w8,1), SV2(h81,1), b1);
          a1 = fdot2_(SV2(w8,2), SV2(h81,2), a1);
          b1 = fdot2_(SV2(w8,3), SV2(h81,3), b1);
        }
      }
      const float pre0 = xp0 + (a0 + b0);
      acts[par][0][tid] = (w==2) ? th_(pre0) : sig_(pre0);
      if constexpr (NR==2){
        const float pre1 = xp1 + (a1 + b1);
        acts[par][1][tid] = (w==2) ? th_(pre1) : sig_(pre1);
      }
      __syncthreads();

      // row 0 update (replicated in all waves; wave 0 stores)
      {
        const float iv = acts[par][0][j];
        const float fv = acts[par][0][64+j];
        const float gv = acts[par][0][128+j];
        const float ov = acts[par][0][192+j];
        c0 = fv*c0 + iv*gv;
        const float h = ov * th_(c0);
        hl0 = h;
        hs4[w][0][j] = (_Float16)h;
        if constexpr (MODE==0)
          if (w == 0){ *q0 = (_Float16)h; q0 += dX; }
      }
      if constexpr (NR==2){
        const float iv = acts[par][1][j];
        const float fv = acts[par][1][64+j];
        const float gv = acts[par][1][128+j];
        const float ov = acts[par][1][192+j];
        c1 = fv*c1 + iv*gv;
        const float h = ov * th_(c1);
        hl1 = h;
        hs4[w][1][j] = (_Float16)h;
        if constexpr (MODE==0)
          if (w == 1){ *q1 = (_Float16)h; q1 += dX; }
      }
    }
  }
  if constexpr (MODE==1){
    if (w == 0) hfin[(size_t)(r0+0)*64 + j] = hl0;
    if constexpr (NR==2)
      if (w == 1) hfin[(size_t)(r0+1)*64 + j] = hl1;
  }
}

// Layer-1 reverse collapses to ONE step from zero state on x1[:,T-1]; fuse with FC.
__global__ __launch_bounds__(256)
void final_fuse(const _Float16* __restrict__ x1, const float* __restrict__ w_ih,
                const float* __restrict__ bvec, const float* __restrict__ hfin,
                const float* __restrict__ fcw, const float* __restrict__ fcb,
                float* __restrict__ out)
{
  const int b = blockIdx.x, tid = threadIdx.x;
  __shared__ float xs[128];
  __shared__ float act[256];
  __shared__ float hall[128];
  if (tid < 128) xs[tid] = (float)x1[((size_t)b*TT + (TT-1))*128 + tid];
  __syncthreads();
  float a = bvec[tid];
  #pragma unroll
  for (int kk=0;kk<32;kk++){
    float4v wv = *reinterpret_cast<const float4v*>(&w_ih[(size_t)tid*128 + kk*4]);
    a += wv[0]*xs[kk*4] + wv[1]*xs[kk*4+1] + wv[2]*xs[kk*4+2] + wv[3]*xs[kk*4+3];
  }
  const int grp = tid>>6;
  act[tid] = (grp==2) ? th_(a) : sig_(a);
  __syncthreads();
  if (tid < 64) {
    float c = act[tid]*act[128+tid];        // c = i*g (c0 = 0)
    float h = act[192+tid]*th_(c);          // h = o*tanh(c)
    hall[64+tid] = h;
    hall[tid] = hfin[(size_t)b*64 + tid];
  }
  __syncthreads();
  if (tid < 3) {
    float acc2 = fcb[tid];
    for (int k=0;k<128;k++) acc2 += fcw[(size_t)tid*128 + k]*hall[k];
    out[(size_t)b*3 + tid] = acc2;
  }
}

extern "C" void kernel_launch(void* const* d_in, const int* in_sizes, int n_in,
                              void* d_out, int out_size, void* d_ws, size_t ws_size,
                              hipStream_t stream) {
  const float* x        = (const float*)d_in[0];
  const float* w_ih_l0f = (const float*)d_in[1];
  const float* w_hh_l0f = (const float*)d_in[2];
  const float* b_l0f    = (const float*)d_in[3];
  const float* w_ih_l0r = (const float*)d_in[4];
  const float* w_hh_l0r = (const float*)d_in[5];
  const float* b_l0r    = (const float*)d_in[6];
  const float* w_ih_l1f = (const float*)d_in[7];
  const float* w_hh_l1f = (const float*)d_in[8];
  const float* b_l1f    = (const float*)d_in[9];
  const float* w_ih_l1r = (const float*)d_in[10];
  const float* b_l1r    = (const float*)d_in[12];
  const float* fc_w     = (const float*)d_in[13];
  const float* fc_b     = (const float*)d_in[14];
  float* out = (float*)d_out;

  const size_t XG_BYTES = (size_t)BB*TT*NG*2;      // xgF then xgR ADJACENT
  const size_t X1_BYTES = (size_t)BB*TT*128*2;
  const size_t HF_BYTES = (size_t)BB*64*4;
  const size_t W16_BYTES = (size_t)147456*2;
  if (ws_size < 2*XG_BYTES + X1_BYTES + HF_BYTES + W16_BYTES) return;
  _Float16* xgF  = (_Float16*)d_ws;
  _Float16* xgR  = (_Float16*)((char*)d_ws + XG_BYTES);
  _Float16* x1   = (_Float16*)((char*)d_ws + 2*XG_BYTES);
  float*    hfin = (float*)   ((char*)d_ws + 2*XG_BYTES + X1_BYTES);
  _Float16* w16  = (_Float16*)((char*)d_ws + 2*XG_BYTES + X1_BYTES + HF_BYTES);
  _Float16* wih_l0f16 = w16;
  _Float16* wih_l0r16 = w16 + 32768;
  _Float16* wih_l1f16 = w16 + 65536;
  _Float16* whh_l0f16 = w16 + 98304;    // whh_l0r16 = +16384 halves (adjacent)
  _Float16* whh_l1f16 = w16 + 131072;

  const int MBLK = (BB*TT)/64;  // 2048

  conv_weights<<<576, 256, 0, stream>>>(w_ih_l0f, w_ih_l0r, w_ih_l1f,
                                        w_hh_l0f, w_hh_l0r, w_hh_l1f, w16);
  // layer 0: both input GEMMs, then fused fwd+rev scan (512 blocks, NR=2)
  gemm_xg<float><<<MBLK, 256, 0, stream>>>(x, wih_l0f16, b_l0f, xgF);
  gemm_xg<float><<<MBLK, 256, 0, stream>>>(x, wih_l0r16, b_l0r, xgR);
  lstm_scan_d<2,0><<<512, 256, 0, stream>>>(xgF, whh_l0f16, 256, x1, nullptr);
  // layer 1 forward (only final h needed): NR=1, 512 blocks
  gemm_xg<_Float16><<<MBLK, 256, 0, stream>>>(x1, wih_l1f16, b_l1f, xgF);
  lstm_scan_d<1,1><<<512, 256, 0, stream>>>(xgF, whh_l1f16, 512, nullptr, hfin);
  // layer 1 reverse one-step + FC
  final_fuse<<<BB, 256, 0, stream>>>(x1, w_ih_l1r, b_l1r, hfin, fc_w, fc_b, out);
}

// Round 16
// 401.627 us; speedup vs baseline: 1.3149x; 1.3149x over previous
//
#include <hip/hip_runtime.h>

#define TT 256   // T
#define BB 512   // B
#define NG 256   // 4*H
#define KIN 128  // input width for both layers

typedef _Float16 half2v __attribute__((ext_vector_type(2)));
typedef _Float16 half4v __attribute__((ext_vector_type(4)));
typedef _Float16 half8v __attribute__((ext_vector_type(8)));
typedef float float4v __attribute__((ext_vector_type(4)));

__device__ __forceinline__ float sig_(float x){ return 1.f/(1.f+__expf(-x)); }
__device__ __forceinline__ float th_(float x){ return fmaf(2.f, 1.f/(1.f+__expf(-2.f*x)), -1.f); }

#if __has_builtin(__builtin_amdgcn_fdot2)
__device__ __forceinline__ float fdot2_(half2v a, half2v b, float c){
  return __builtin_amdgcn_fdot2(a, b, c, false);
}
#else
__device__ __forceinline__ float fdot2_(half2v a, half2v b, float c){
  return c + (float)a[0]*(float)b[0] + (float)a[1]*(float)b[1];
}
#endif

#define SV2(v,k) __builtin_shufflevector((v),(v), 2*(k), 2*(k)+1)

__device__ __forceinline__ half4v ld4h(const float* p){
  float4v v = *reinterpret_cast<const float4v*>(p);
  half4v h; h[0]=(_Float16)v[0]; h[1]=(_Float16)v[1]; h[2]=(_Float16)v[2]; h[3]=(_Float16)v[3];
  return h;
}

// ---- one-shot weight conversion fp32 -> fp16 into ws pool ----
// halves offsets: wih_l0f 0, wih_l0r 32768, wih_l1f 65536,
//                 whh_l0f 98304, whh_l0r 114688, whh_l1f 131072  (total 147456)
__global__ __launch_bounds__(256)
void conv_weights(const float* __restrict__ s0, const float* __restrict__ s1,
                  const float* __restrict__ s2, const float* __restrict__ s3,
                  const float* __restrict__ s4, const float* __restrict__ s5,
                  _Float16* __restrict__ dst)
{
  const int bid = blockIdx.x, tid = threadIdx.x;
  const float* src; int off, idx;
  if (bid < 128)      { src=s0; off=0;      idx=bid*256+tid; }
  else if (bid < 256) { src=s1; off=32768;  idx=(bid-128)*256+tid; }
  else if (bid < 384) { src=s2; off=65536;  idx=(bid-256)*256+tid; }
  else if (bid < 448) { src=s3; off=98304;  idx=(bid-384)*256+tid; }
  else if (bid < 512) { src=s4; off=114688; idx=(bid-448)*256+tid; }
  else                { src=s5; off=131072; idx=(bid-512)*256+tid; }
  dst[off+idx] = (_Float16)src[idx];
}

// C[m][n] = sum_k A[m][k]*W[n][k] + bias[n], written fp16.
template<typename AT>
__global__ __launch_bounds__(256)
void gemm_xg(const AT* __restrict__ A, const _Float16* __restrict__ W16,
             const float* __restrict__ bias, _Float16* __restrict__ Cout)
{
  __shared__ __align__(16) _Float16 aL[64][72];
  __shared__ __align__(16) _Float16 wL[256][72];
  const int tid  = threadIdx.x;
  const int wave = tid >> 6;
  const int lane = tid & 63;
  const int lr   = lane & 15;
  const int kg   = lane >> 4;
  const size_t m0 = (size_t)blockIdx.x * 64;

  float4v acc[4][4];
  #pragma unroll
  for (int a=0;a<4;a++)
    #pragma unroll
    for (int b=0;b<4;b++)
      acc[a][b] = float4v{0.f,0.f,0.f,0.f};

  for (int kc = 0; kc < KIN; kc += 64) {
    if constexpr (__is_same(AT, float)) {
      #pragma unroll
      for (int q=0;q<4;q++){
        int fi = tid + q*256;
        int r = fi >> 4, c4 = (fi & 15)*4;
        *reinterpret_cast<half4v*>(&aL[r][c4]) = ld4h(&A[(m0+(size_t)r)*KIN + kc + c4]);
      }
    } else {
      #pragma unroll
      for (int q=0;q<2;q++){
        int fi = tid + q*256;
        int r = fi >> 3, c8 = (fi & 7)*8;
        *reinterpret_cast<half8v*>(&aL[r][c8]) =
            *reinterpret_cast<const half8v*>(&A[(m0+(size_t)r)*KIN + kc + c8]);
      }
    }
    #pragma unroll
    for (int q=0;q<8;q++){
      int fi = tid + q*256;
      int n = fi >> 3, c8 = (fi & 7)*8;
      *reinterpret_cast<half8v*>(&wL[n][c8]) =
          *reinterpret_cast<const half8v*>(&W16[(size_t)n*KIN + kc + c8]);
    }
    __syncthreads();
    #pragma unroll
    for (int ks=0; ks<64; ks+=32){
      half8v af[4], bf[4];
      #pragma unroll
      for (int rt=0;rt<4;rt++)
        af[rt] = *reinterpret_cast<const half8v*>(&aL[rt*16+lr][ks + kg*8]);
      #pragma unroll
      for (int ct=0;ct<4;ct++)
        bf[ct] = *reinterpret_cast<const half8v*>(&wL[wave*64 + ct*16 + lr][ks + kg*8]);
      #pragma unroll
      for (int rt=0;rt<4;rt++)
        #pragma unroll
        for (int ct=0;ct<4;ct++)
          acc[rt][ct] = __builtin_amdgcn_mfma_f32_16x16x32_f16(af[rt], bf[ct], acc[rt][ct], 0,0,0);
    }
    __syncthreads();
  }
  #pragma unroll
  for (int ct=0;ct<4;ct++){
    const int col = wave*64 + ct*16 + lr;
    const float bv = bias[col];
    #pragma unroll
    for (int rt=0;rt<4;rt++){
      const size_t rbase = m0 + rt*16 + kg*4;
      #pragma unroll
      for (int i=0;i<4;i++)
        Cout[(rbase+(size_t)i)*NG + col] = (_Float16)(acc[rt][ct][i] + bv);
    }
  }
}

// LSTM scan (r8 = session-best structure): 4 waves/block, WAVE w OWNS GATE w.
// Lane j of wave w holds w_hh row (w*64+j). Per step: 32 fdot2 -> act ->
// write acts[t&1][w*64+j] -> ONE barrier -> all waves redundantly read
// i/f/g/o, update private replicated c, h -> wave-private hs4[w]
// (same-wave DS ordering, no 2nd barrier). acts ping-pong by t parity.
// xg: 1 coalesced b16 load/lane/step via depth-8 register ring (static idx).
template<int MODE>
__global__ __launch_bounds__(256, 4)
void lstm_scan_g4(const _Float16* __restrict__ xgPool,   // fwd at 0, rev at +BB*TT*NG
                  const _Float16* __restrict__ whhPool,  // fwd at 0, rev at +16384
                  int nF,
                  _Float16* __restrict__ x1out, float* __restrict__ hfin)
{
  const int tid = threadIdx.x;
  const int w   = tid >> 6;        // wave id = gate id (0:i 1:f 2:g 3:o)
  const int j   = tid & 63;        // hidden unit / gate row within gate
  const bool rev = (int)blockIdx.x >= nF;
  const int b = rev ? ((int)blockIdx.x - nF) : (int)blockIdx.x;
  const _Float16* xg  = xgPool  + (rev ? (size_t)BB*TT*NG : 0);
  const _Float16* whh = whhPool + (rev ? (size_t)16384 : 0);

  __shared__ __align__(16) float acts[2][256];      // ping-pong by t parity
  __shared__ __align__(16) _Float16 hs4[4][64];     // per-wave private h copy

  // gate-w row j of w_hh: 64 halves = 8 half8v = 32 VGPRs
  half8v wreg[8];
  #pragma unroll
  for (int q=0;q<8;q++)
    wreg[q] = *reinterpret_cast<const half8v*>(&whh[(size_t)(w*64 + j)*64 + q*8]);
  // PIN: discourage rematerialization of the weight loads
  #pragma unroll
  for (int q=0;q<8;q++)
    asm volatile("" : "+v"(wreg[q]));

  hs4[w][j] = (_Float16)0.f;     // same-wave write; ordered vs our own reads
  float c = 0.f, h_last = 0.f;

  const _Float16* xgb = xg + (size_t)b*TT*NG + w*64 + j;
  _Float16 ring[8];              // static indices after unroll-8
  #pragma unroll
  for (int u=0;u<8;u++)
    ring[u] = xgb[(size_t)(rev ? (TT-1-u) : u) * NG];

  for (int tb=0; tb<TT; tb+=8){
    #pragma unroll
    for (int u=0;u<8;u++){
      const int tt = tb + u;
      const int t  = rev ? (TT-1-tt) : tt;

      const float xp = (float)ring[u];          // loaded 8 steps ago
      const int tf = tt + 8;
      if (tf < TT)
        ring[u] = xgb[(size_t)(rev ? (TT-1-tf) : tf) * NG];

      // dot: w_hh[gate w, row j] . h   (2 fp32 chains)
      float a=0.f, a2=0.f;
      #pragma unroll
      for (int q=0;q<8;q++){
        const half8v h8 = *reinterpret_cast<const half8v*>(&hs4[w][q*8]);  // broadcast read
        a  = fdot2_(SV2(wreg[q],0), SV2(h8,0), a);
        a2 = fdot2_(SV2(wreg[q],1), SV2(h8,1), a2);
        a  = fdot2_(SV2(wreg[q],2), SV2(h8,2), a);
        a2 = fdot2_(SV2(wreg[q],3), SV2(h8,3), a2);
      }
      const float pre = xp + (a + a2);
      acts[tt&1][w*64 + j] = (w==2) ? th_(pre) : sig_(pre);   // wave-uniform branch
      __syncthreads();

      const float iv = acts[tt&1][j];
      const float fv = acts[tt&1][64+j];
      const float gv = acts[tt&1][128+j];
      const float ov = acts[tt&1][192+j];
      c = fv*c + iv*gv;                        // replicated identically in all 4 waves
      const float h = ov * th_(c);
      h_last = h;
      hs4[w][j] = (_Float16)h;                 // private copy; no barrier needed
      if constexpr (MODE==0)
        if (w == 0)
          x1out[((size_t)b*TT + t)*128 + (rev ? 64 : 0) + j] = (_Float16)h;
    }
  }
  if constexpr (MODE==1)
    if (w == 0)
      hfin[(size_t)b*64 + j] = h_last;
}

// Layer-1 reverse collapses to ONE step from zero state on x1[:,T-1]; fuse with FC.
__global__ __launch_bounds__(256)
void final_fuse(const _Float16* __restrict__ x1, const float* __restrict__ w_ih,
                const float* __restrict__ bvec, const float* __restrict__ hfin,
                const float* __restrict__ fcw, const float* __restrict__ fcb,
                float* __restrict__ out)
{
  const int b = blockIdx.x, tid = threadIdx.x;
  __shared__ float xs[128];
  __shared__ float act[256];
  __shared__ float hall[128];
  if (tid < 128) xs[tid] = (float)x1[((size_t)b*TT + (TT-1))*128 + tid];
  __syncthreads();
  float a = bvec[tid];
  #pragma unroll
  for (int kk=0;kk<32;kk++){
    float4v wv = *reinterpret_cast<const float4v*>(&w_ih[(size_t)tid*128 + kk*4]);
    a += wv[0]*xs[kk*4] + wv[1]*xs[kk*4+1] + wv[2]*xs[kk*4+2] + wv[3]*xs[kk*4+3];
  }
  const int grp = tid>>6;
  act[tid] = (grp==2) ? th_(a) : sig_(a);
  __syncthreads();
  if (tid < 64) {
    float c = act[tid]*act[128+tid];        // c = i*g (c0 = 0)
    float h = act[192+tid]*th_(c);          // h = o*tanh(c)
    hall[64+tid] = h;
    hall[tid] = hfin[(size_t)b*64 + tid];
  }
  __syncthreads();
  if (tid < 3) {
    float acc2 = fcb[tid];
    for (int k=0;k<128;k++) acc2 += fcw[(size_t)tid*128 + k]*hall[k];
    out[(size_t)b*3 + tid] = acc2;
  }
}

extern "C" void kernel_launch(void* const* d_in, const int* in_sizes, int n_in,
                              void* d_out, int out_size, void* d_ws, size_t ws_size,
                              hipStream_t stream) {
  const float* x        = (const float*)d_in[0];
  const float* w_ih_l0f = (const float*)d_in[1];
  const float* w_hh_l0f = (const float*)d_in[2];
  const float* b_l0f    = (const float*)d_in[3];
  const float* w_ih_l0r = (const float*)d_in[4];
  const float* w_hh_l0r = (const float*)d_in[5];
  const float* b_l0r    = (const float*)d_in[6];
  const float* w_ih_l1f = (const float*)d_in[7];
  const float* w_hh_l1f = (const float*)d_in[8];
  const float* b_l1f    = (const float*)d_in[9];
  const float* w_ih_l1r = (const float*)d_in[10];
  const float* b_l1r    = (const float*)d_in[12];
  const float* fc_w     = (const float*)d_in[13];
  const float* fc_b     = (const float*)d_in[14];
  float* out = (float*)d_out;

  // workspace layout (bytes)
  const size_t XG_BYTES = (size_t)BB*TT*NG*2;      // xgF then xgR ADJACENT
  const size_t X1_BYTES = (size_t)BB*TT*128*2;
  const size_t HF_BYTES = (size_t)BB*64*4;
  const size_t W16_BYTES = (size_t)147456*2;
  if (ws_size < 2*XG_BYTES + X1_BYTES + HF_BYTES + W16_BYTES) return;
  _Float16* xgF  = (_Float16*)d_ws;
  _Float16* xgR  = (_Float16*)((char*)d_ws + XG_BYTES);   // = xgF + BB*TT*NG halves
  _Float16* x1   = (_Float16*)((char*)d_ws + 2*XG_BYTES);
  float*    hfin = (float*)   ((char*)d_ws + 2*XG_BYTES + X1_BYTES);
  _Float16* w16  = (_Float16*)((char*)d_ws + 2*XG_BYTES + X1_BYTES + HF_BYTES);
  _Float16* wih_l0f16 = w16;
  _Float16* wih_l0r16 = w16 + 32768;
  _Float16* wih_l1f16 = w16 + 65536;
  _Float16* whh_l0f16 = w16 + 98304;    // whh_l0r16 = +16384 halves (adjacent)
  _Float16* whh_l1f16 = w16 + 131072;

  const int MBLK = (BB*TT)/64;  // 2048

  conv_weights<<<576, 256, 0, stream>>>(w_ih_l0f, w_ih_l0r, w_ih_l1f,
                                        w_hh_l0f, w_hh_l0r, w_hh_l1f, w16);
  // layer 0: both input GEMMs, then fused fwd+rev scan (1024 4-wave blocks)
  gemm_xg<float><<<MBLK, 256, 0, stream>>>(x, wih_l0f16, b_l0f, xgF);
  gemm_xg<float><<<MBLK, 256, 0, stream>>>(x, wih_l0r16, b_l0r, xgR);
  lstm_scan_g4<0><<<1024, 256, 0, stream>>>(xgF, whh_l0f16, 512, x1, nullptr);
  // layer 1 forward (only final h needed)
  gemm_xg<_Float16><<<MBLK, 256, 0, stream>>>(x1, wih_l1f16, b_l1f, xgF);
  lstm_scan_g4<1><<<512, 256, 0, stream>>>(xgF, whh_l1f16, 512, nullptr, hfin);
  // layer 1 reverse one-step + FC
  final_fuse<<<BB, 256, 0, stream>>>(x1, w_ih_l1r, b_l1r, hfin, fc_w, fc_b, out);
}

// Round 17
// 400.411 us; speedup vs baseline: 1.3189x; 1.0030x over previous
//
#include <hip/hip_runtime.h>

#define TT 256   // T
#define BB 512   // B
#define NG 256   // 4*H
#define KIN 128  // input width for both layers

typedef _Float16 half2v __attribute__((ext_vector_type(2)));
typedef _Float16 half4v __attribute__((ext_vector_type(4)));
typedef _Float16 half8v __attribute__((ext_vector_type(8)));
typedef float float4v __attribute__((ext_vector_type(4)));

__device__ __forceinline__ float sig_(float x){ return 1.f/(1.f+__expf(-x)); }
__device__ __forceinline__ float th_(float x){ return fmaf(2.f, 1.f/(1.f+__expf(-2.f*x)), -1.f); }

#if __has_builtin(__builtin_amdgcn_fdot2)
__device__ __forceinline__ float fdot2_(half2v a, half2v b, float c){
  return __builtin_amdgcn_fdot2(a, b, c, false);
}
#else
__device__ __forceinline__ float fdot2_(half2v a, half2v b, float c){
  return c + (float)a[0]*(float)b[0] + (float)a[1]*(float)b[1];
}
#endif

#define SV2(v,k) __builtin_shufflevector((v),(v), 2*(k), 2*(k)+1)

__device__ __forceinline__ half4v ld4h(const float* p){
  float4v v = *reinterpret_cast<const float4v*>(p);
  half4v h; h[0]=(_Float16)v[0]; h[1]=(_Float16)v[1]; h[2]=(_Float16)v[2]; h[3]=(_Float16)v[3];
  return h;
}

// ---- one-shot weight conversion fp32 -> fp16 into ws pool ----
// halves offsets: wih_l0f 0, wih_l0r 32768, wih_l1f 65536,
//                 whh_l0f 98304, whh_l0r 114688, whh_l1f 131072  (total 147456)
__global__ __launch_bounds__(256)
void conv_weights(const float* __restrict__ s0, const float* __restrict__ s1,
                  const float* __restrict__ s2, const float* __restrict__ s3,
                  const float* __restrict__ s4, const float* __restrict__ s5,
                  _Float16* __restrict__ dst)
{
  const int bid = blockIdx.x, tid = threadIdx.x;
  const float* src; int off, idx;
  if (bid < 128)      { src=s0; off=0;      idx=bid*256+tid; }
  else if (bid < 256) { src=s1; off=32768;  idx=(bid-128)*256+tid; }
  else if (bid < 384) { src=s2; off=65536;  idx=(bid-256)*256+tid; }
  else if (bid < 448) { src=s3; off=98304;  idx=(bid-384)*256+tid; }
  else if (bid < 512) { src=s4; off=114688; idx=(bid-448)*256+tid; }
  else                { src=s5; off=131072; idx=(bid-512)*256+tid; }
  dst[off+idx] = (_Float16)src[idx];
}

// C[m][n] = sum_k A[m][k]*W[n][k] + bias[n], written fp16.
template<typename AT>
__global__ __launch_bounds__(256)
void gemm_xg(const AT* __restrict__ A, const _Float16* __restrict__ W16,
             const float* __restrict__ bias, _Float16* __restrict__ Cout)
{
  __shared__ __align__(16) _Float16 aL[64][72];
  __shared__ __align__(16) _Float16 wL[256][72];
  const int tid  = threadIdx.x;
  const int wave = tid >> 6;
  const int lane = tid & 63;
  const int lr   = lane & 15;
  const int kg   = lane >> 4;
  const size_t m0 = (size_t)blockIdx.x * 64;

  float4v acc[4][4];
  #pragma unroll
  for (int a=0;a<4;a++)
    #pragma unroll
    for (int b=0;b<4;b++)
      acc[a][b] = float4v{0.f,0.f,0.f,0.f};

  for (int kc = 0; kc < KIN; kc += 64) {
    if constexpr (__is_same(AT, float)) {
      #pragma unroll
      for (int q=0;q<4;q++){
        int fi = tid + q*256;
        int r = fi >> 4, c4 = (fi & 15)*4;
        *reinterpret_cast<half4v*>(&aL[r][c4]) = ld4h(&A[(m0+(size_t)r)*KIN + kc + c4]);
      }
    } else {
      #pragma unroll
      for (int q=0;q<2;q++){
        int fi = tid + q*256;
        int r = fi >> 3, c8 = (fi & 7)*8;
        *reinterpret_cast<half8v*>(&aL[r][c8]) =
            *reinterpret_cast<const half8v*>(&A[(m0+(size_t)r)*KIN + kc + c8]);
      }
    }
    #pragma unroll
    for (int q=0;q<8;q++){
      int fi = tid + q*256;
      int n = fi >> 3, c8 = (fi & 7)*8;
      *reinterpret_cast<half8v*>(&wL[n][c8]) =
          *reinterpret_cast<const half8v*>(&W16[(size_t)n*KIN + kc + c8]);
    }
    __syncthreads();
    #pragma unroll
    for (int ks=0; ks<64; ks+=32){
      half8v af[4], bf[4];
      #pragma unroll
      for (int rt=0;rt<4;rt++)
        af[rt] = *reinterpret_cast<const half8v*>(&aL[rt*16+lr][ks + kg*8]);
      #pragma unroll
      for (int ct=0;ct<4;ct++)
        bf[ct] = *reinterpret_cast<const half8v*>(&wL[wave*64 + ct*16 + lr][ks + kg*8]);
      #pragma unroll
      for (int rt=0;rt<4;rt++)
        #pragma unroll
        for (int ct=0;ct<4;ct++)
          acc[rt][ct] = __builtin_amdgcn_mfma_f32_16x16x32_f16(af[rt], bf[ct], acc[rt][ct], 0,0,0);
    }
    __syncthreads();
  }
  #pragma unroll
  for (int ct=0;ct<4;ct++){
    const int col = wave*64 + ct*16 + lr;
    const float bv = bias[col];
    #pragma unroll
    for (int rt=0;rt<4;rt++){
      const size_t rbase = m0 + rt*16 + kg*4;
      #pragma unroll
      for (int i=0;i<4;i++)
        Cout[(rbase+(size_t)i)*NG + col] = (_Float16)(acc[rt][ct][i] + bv);
    }
  }
}

// LSTM scan r17 = r8 skeleton (4 waves/block, wave=gate, private hs4,
// ping-pong acts, ONE barrier/step, ring-8 xg prefetch) with two local edits:
//  * weight pins moved INSIDE the step loop: volatile asm "+v" each step
//    forces wreg into VGPRs at every iteration -> keeping them resident in
//    VGPRs (fits: ~70 < 128 @ 4 waves/EU) beats paying 32 accvgpr_read
//    copies/step (r8/r16: VGPR=36 -> weights parked in AGPRs).
//  * xg ring refill and x1out store via single pointers advanced by a
//    constant stride (kills per-step index multiplies).
template<int MODE>
__global__ __launch_bounds__(256, 4)
void lstm_scan_g4(const _Float16* __restrict__ xgPool,   // fwd at 0, rev at +BB*TT*NG
                  const _Float16* __restrict__ whhPool,  // fwd at 0, rev at +16384
                  int nF,
                  _Float16* __restrict__ x1out, float* __restrict__ hfin)
{
  const int tid = threadIdx.x;
  const int w   = tid >> 6;        // wave id = gate id (0:i 1:f 2:g 3:o)
  const int j   = tid & 63;        // hidden unit / gate row within gate
  const bool rev = (int)blockIdx.x >= nF;
  const int b = rev ? ((int)blockIdx.x - nF) : (int)blockIdx.x;
  const _Float16* xg  = xgPool  + (rev ? (size_t)BB*TT*NG : 0);
  const _Float16* whh = whhPool + (rev ? (size_t)16384 : 0);

  __shared__ __align__(16) float acts[2][256];      // ping-pong by t parity
  __shared__ __align__(16) _Float16 hs4[4][64];     // per-wave private h copy

  // gate-w row j of w_hh: 64 halves = 8 half8v = 32 VGPRs
  half8v wreg[8];
  #pragma unroll
  for (int q=0;q<8;q++)
    wreg[q] = *reinterpret_cast<const half8v*>(&whh[(size_t)(w*64 + j)*64 + q*8]);

  hs4[w][j] = (_Float16)0.f;     // same-wave write; ordered vs our own reads
  float c = 0.f, h_last = 0.f;

  // xg prefetch pointer: sequential in scan order, stride dT
  const ptrdiff_t dT = rev ? -(ptrdiff_t)NG : (ptrdiff_t)NG;
  const _Float16* pld = xg + (size_t)b*TT*NG + w*64 + j
                      + (rev ? (size_t)(TT-1)*NG : 0);
  _Float16 ring[8];              // static indices after unroll-8
  #pragma unroll
  for (int u=0;u<8;u++){ ring[u] = *pld; pld += dT; }

  // x1 store pointer (wave 0 only uses it), stride dX per step
  const ptrdiff_t dX = rev ? -(ptrdiff_t)128 : (ptrdiff_t)128;
  _Float16* qx = x1out
      ? x1out + ((size_t)b*TT + (rev ? TT-1 : 0))*128 + (rev ? 64 : 0) + j
      : nullptr;

  for (int tb=0; tb<TT; tb+=8){
    #pragma unroll
    for (int u=0;u<8;u++){
      const int tt = tb + u;

      // PIN each step: wreg must be in VGPRs here; re-load is impossible
      // (asm output), so resident-in-VGPR becomes the cheapest allocation.
      #pragma unroll
      for (int q=0;q<8;q++)
        asm volatile("" : "+v"(wreg[q]));

      const float xp = (float)ring[u];          // loaded 8 steps ago
      if (tt+8 < TT){ ring[u] = *pld; pld += dT; }

      // dot: w_hh[gate w, row j] . h   (2 fp32 chains)
      float a=0.f, a2=0.f;
      #pragma unroll
      for (int q=0;q<8;q++){
        const half8v h8 = *reinterpret_cast<const half8v*>(&hs4[w][q*8]);  // broadcast read
        a  = fdot2_(SV2(wreg[q],0), SV2(h8,0), a);
        a2 = fdot2_(SV2(wreg[q],1), SV2(h8,1), a2);
        a  = fdot2_(SV2(wreg[q],2), SV2(h8,2), a);
        a2 = fdot2_(SV2(wreg[q],3), SV2(h8,3), a2);
      }
      const float pre = xp + (a + a2);
      acts[tt&1][w*64 + j] = (w==2) ? th_(pre) : sig_(pre);   // wave-uniform branch
      __syncthreads();

      const float iv = acts[tt&1][j];
      const float fv = acts[tt&1][64+j];
      const float gv = acts[tt&1][128+j];
      const float ov = acts[tt&1][192+j];
      c = fv*c + iv*gv;                        // replicated identically in all 4 waves
      const float h = ov * th_(c);
      h_last = h;
      hs4[w][j] = (_Float16)h;                 // private copy; no barrier needed
      if constexpr (MODE==0)
        if (w == 0){ *qx = (_Float16)h; qx += dX; }
    }
  }
  if constexpr (MODE==1)
    if (w == 0)
      hfin[(size_t)b*64 + j] = h_last;
}

// Layer-1 reverse collapses to ONE step from zero state on x1[:,T-1]; fuse with FC.
__global__ __launch_bounds__(256)
void final_fuse(const _Float16* __restrict__ x1, const float* __restrict__ w_ih,
                const float* __restrict__ bvec, const float* __restrict__ hfin,
                const float* __restrict__ fcw, const float* __restrict__ fcb,
                float* __restrict__ out)
{
  const int b = blockIdx.x, tid = threadIdx.x;
  __shared__ float xs[128];
  __shared__ float act[256];
  __shared__ float hall[128];
  if (tid < 128) xs[tid] = (float)x1[((size_t)b*TT + (TT-1))*128 + tid];
  __syncthreads();
  float a = bvec[tid];
  #pragma unroll
  for (int kk=0;kk<32;kk++){
    float4v wv = *reinterpret_cast<const float4v*>(&w_ih[(size_t)tid*128 + kk*4]);
    a += wv[0]*xs[kk*4] + wv[1]*xs[kk*4+1] + wv[2]*xs[kk*4+2] + wv[3]*xs[kk*4+3];
  }
  const int grp = tid>>6;
  act[tid] = (grp==2) ? th_(a) : sig_(a);
  __syncthreads();
  if (tid < 64) {
    float c = act[tid]*act[128+tid];        // c = i*g (c0 = 0)
    float h = act[192+tid]*th_(c);          // h = o*tanh(c)
    hall[64+tid] = h;
    hall[tid] = hfin[(size_t)b*64 + tid];
  }
  __syncthreads();
  if (tid < 3) {
    float acc2 = fcb[tid];
    for (int k=0;k<128;k++) acc2 += fcw[(size_t)tid*128 + k]*hall[k];
    out[(size_t)b*3 + tid] = acc2;
  }
}

extern "C" void kernel_launch(void* const* d_in, const int* in_sizes, int n_in,
                              void* d_out, int out_size, void* d_ws, size_t ws_size,
                              hipStream_t stream) {
  const float* x        = (const float*)d_in[0];
  const float* w_ih_l0f = (const float*)d_in[1];
  const float* w_hh_l0f = (const float*)d_in[2];
  const float* b_l0f    = (const float*)d_in[3];
  const float* w_ih_l0r = (const float*)d_in[4];
  const float* w_hh_l0r = (const float*)d_in[5];
  const float* b_l0r    = (const float*)d_in[6];
  const float* w_ih_l1f = (const float*)d_in[7];
  const float* w_hh_l1f = (const float*)d_in[8];
  const float* b_l1f    = (const float*)d_in[9];
  const float* w_ih_l1r = (const float*)d_in[10];
  const float* b_l1r    = (const float*)d_in[12];
  const float* fc_w     = (const float*)d_in[13];
  const float* fc_b     = (const float*)d_in[14];
  float* out = (float*)d_out;

  // workspace layout (bytes)
  const size_t XG_BYTES = (size_t)BB*TT*NG*2;      // xgF then xgR ADJACENT
  const size_t X1_BYTES = (size_t)BB*TT*128*2;
  const size_t HF_BYTES = (size_t)BB*64*4;
  const size_t W16_BYTES = (size_t)147456*2;
  if (ws_size < 2*XG_BYTES + X1_BYTES + HF_BYTES + W16_BYTES) return;
  _Float16* xgF  = (_Float16*)d_ws;
  _Float16* xgR  = (_Float16*)((char*)d_ws + XG_BYTES);   // = xgF + BB*TT*NG halves
  _Float16* x1   = (_Float16*)((char*)d_ws + 2*XG_BYTES);
  float*    hfin = (float*)   ((char*)d_ws + 2*XG_BYTES + X1_BYTES);
  _Float16* w16  = (_Float16*)((char*)d_ws + 2*XG_BYTES + X1_BYTES + HF_BYTES);
  _Float16* wih_l0f16 = w16;
  _Float16* wih_l0r16 = w16 + 32768;
  _Float16* wih_l1f16 = w16 + 65536;
  _Float16* whh_l0f16 = w16 + 98304;    // whh_l0r16 = +16384 halves (adjacent)
  _Float16* whh_l1f16 = w16 + 131072;

  const int MBLK = (BB*TT)/64;  // 2048

  conv_weights<<<576, 256, 0, stream>>>(w_ih_l0f, w_ih_l0r, w_ih_l1f,
                                        w_hh_l0f, w_hh_l0r, w_hh_l1f, w16);
  // layer 0: both input GEMMs, then fused fwd+rev scan (1024 4-wave blocks)
  gemm_xg<float><<<MBLK, 256, 0, stream>>>(x, wih_l0f16, b_l0f, xgF);
  gemm_xg<float><<<MBLK, 256, 0, stream>>>(x, wih_l0r16, b_l0r, xgR);
  lstm_scan_g4<0><<<1024, 256, 0, stream>>>(xgF, whh_l0f16, 512, x1, nullptr);
  // layer 1 forward (only final h needed)
  gemm_xg<_Float16><<<MBLK, 256, 0, stream>>>(x1, wih_l1f16, b_l1f, xgF);
  lstm_scan_g4<1><<<512, 256, 0, stream>>>(xgF, whh_l1f16, 512, nullptr, hfin);
  // layer 1 reverse one-step + FC
  final_fuse<<<BB, 256, 0, stream>>>(x1, w_ih_l1r, b_l1r, hfin, fc_w, fc_b, out);
}